// Round 2
// baseline (448.453 us; speedup 1.0000x reference)
//
#include <hip/hip_runtime.h>

typedef __attribute__((ext_vector_type(8))) short bf16x8;
typedef __attribute__((ext_vector_type(4))) float f32x4;

__device__ __forceinline__ unsigned short f2bf(float f) {
  unsigned int u = __builtin_bit_cast(unsigned int, f);
  u += 0x7fffu + ((u >> 16) & 1u);   // round-to-nearest-even
  return (unsigned short)(u >> 16);
}

__device__ __forceinline__ bf16x8 cvt8(float4 a, float4 b) {
  bf16x8 t;
  t[0] = (short)f2bf(a.x); t[1] = (short)f2bf(a.y);
  t[2] = (short)f2bf(a.z); t[3] = (short)f2bf(a.w);
  t[4] = (short)f2bf(b.x); t[5] = (short)f2bf(b.y);
  t[6] = (short)f2bf(b.z); t[7] = (short)f2bf(b.w);
  return t;
}

// ---------------------------------------------------------------------------
// K1/K3: GEMM C[M][N] = A[M][K] * B[K][N] (+bias), bf16 MFMA, fp32 accum.
// A: fp32 (K1) or bf16 ws (K3); B: fp32 (weights); C: bf16 ws (K1) or fp32 out (K3).
// tile 128x64, BK=32, 256 threads (4 waves as 2x2 of 64x32 per-wave tiles)
// ---------------------------------------------------------------------------
template <bool A_IS_F32, bool C_IS_F32>
__global__ __launch_bounds__(256) void gemm_kernel(
    const void* __restrict__ Av,
    const float* __restrict__ B,
    void* __restrict__ Cv,
    const float* __restrict__ bias,  // nullable, [N] fp32 (only used when C_IS_F32)
    int M, int N, int K)
{
  __shared__ unsigned short As[128][40];  // +8 pad: 80B row stride kills bank conflicts
  __shared__ unsigned short Bs[64][40];   // transposed [n][k]

  const int tid  = threadIdx.x;
  const int bm   = blockIdx.x * 128;
  const int bn   = blockIdx.y * 64;
  const int lane = tid & 63;
  const int wave = tid >> 6;
  const int wr   = (wave >> 1) * 64;
  const int wc   = (wave & 1) * 32;
  const int l15  = lane & 15;
  const int quad = lane >> 4;

  f32x4 acc[4][2];
#pragma unroll
  for (int r = 0; r < 4; ++r)
#pragma unroll
    for (int c = 0; c < 2; ++c) {
      f32x4 z = {0.f, 0.f, 0.f, 0.f};
      acc[r][c] = z;
    }

  const int ar  = tid >> 2;        // 0..63  (A stage row)
  const int ac  = (tid & 3) * 8;   // 0/8/16/24
  const int bkr = tid >> 3;        // 0..31  (B stage k-row)
  const int bn8 = (tid & 7) * 8;   // 0..56

  for (int kk = 0; kk < K; kk += 32) {
    // ---- stage A tile: 128 rows x 32 k ----
    if constexpr (A_IS_F32) {
      const float* A = (const float*)Av;
      const float* p0 = A + (size_t)(bm + ar) * K + kk + ac;
      const float* p1 = A + (size_t)(bm + ar + 64) * K + kk + ac;
      float4 a0 = *reinterpret_cast<const float4*>(p0);
      float4 a1 = *reinterpret_cast<const float4*>(p0 + 4);
      float4 b0 = *reinterpret_cast<const float4*>(p1);
      float4 b1 = *reinterpret_cast<const float4*>(p1 + 4);
      *reinterpret_cast<bf16x8*>(&As[ar][ac])      = cvt8(a0, a1);
      *reinterpret_cast<bf16x8*>(&As[ar + 64][ac]) = cvt8(b0, b1);
    } else {
      const unsigned short* A = (const unsigned short*)Av;
      *reinterpret_cast<uint4*>(&As[ar][ac]) =
          *reinterpret_cast<const uint4*>(A + (size_t)(bm + ar) * K + kk + ac);
      *reinterpret_cast<uint4*>(&As[ar + 64][ac]) =
          *reinterpret_cast<const uint4*>(A + (size_t)(bm + ar + 64) * K + kk + ac);
    }
    // ---- stage B tile transposed: Bs[n][k], fp32 -> bf16 ----
    {
      const float* p = B + (size_t)(kk + bkr) * N + bn + bn8;
      float4 f0 = *reinterpret_cast<const float4*>(p);
      float4 f1 = *reinterpret_cast<const float4*>(p + 4);
      Bs[bn8 + 0][bkr] = f2bf(f0.x);
      Bs[bn8 + 1][bkr] = f2bf(f0.y);
      Bs[bn8 + 2][bkr] = f2bf(f0.z);
      Bs[bn8 + 3][bkr] = f2bf(f0.w);
      Bs[bn8 + 4][bkr] = f2bf(f1.x);
      Bs[bn8 + 5][bkr] = f2bf(f1.y);
      Bs[bn8 + 6][bkr] = f2bf(f1.z);
      Bs[bn8 + 7][bkr] = f2bf(f1.w);
    }
    __syncthreads();

    bf16x8 bf0 = *reinterpret_cast<const bf16x8*>(&Bs[wc + l15][quad * 8]);
    bf16x8 bf1 = *reinterpret_cast<const bf16x8*>(&Bs[wc + 16 + l15][quad * 8]);
#pragma unroll
    for (int rt = 0; rt < 4; ++rt) {
      bf16x8 af = *reinterpret_cast<const bf16x8*>(&As[wr + rt * 16 + l15][quad * 8]);
      acc[rt][0] = __builtin_amdgcn_mfma_f32_16x16x32_bf16(af, bf0, acc[rt][0], 0, 0, 0);
      acc[rt][1] = __builtin_amdgcn_mfma_f32_16x16x32_bf16(af, bf1, acc[rt][1], 0, 0, 0);
    }
    __syncthreads();
  }

  // epilogue: D[row=quad*4+i][col=l15] per 16x16 tile (verified C/D layout)
#pragma unroll
  for (int rt = 0; rt < 4; ++rt) {
#pragma unroll
    for (int ct = 0; ct < 2; ++ct) {
#pragma unroll
      for (int i = 0; i < 4; ++i) {
        int row = bm + wr + rt * 16 + quad * 4 + i;
        int col = bn + wc + ct * 16 + l15;
        float v = acc[rt][ct][i];
        if constexpr (C_IS_F32) {
          if (bias) v += bias[col];
          ((float*)Cv)[(size_t)row * N + col] = v;
        } else {
          ((unsigned short*)Cv)[(size_t)row * N + col] = f2bf(v);
        }
      }
    }
  }
}

// ---------------------------------------------------------------------------
// K2: masked softmax attention, one workgroup per (s,b,h).
// QKV ws layout: [t = sb*256+n][768] bf16, cols 0..255=Q, 256..511=K, 512..767=V
// Each wave owns 64 Q rows, processed as 4 blocks of 16 rows.
// ---------------------------------------------------------------------------
#define SCALE_F 0.17677669529663689f

__global__ __launch_bounds__(256) void attn_kernel(
    const unsigned short* __restrict__ QKV,
    const int* __restrict__ mask,        // [64][256][256] int32
    unsigned short* __restrict__ Aout)   // [65536][256] bf16 ws
{
  __shared__ unsigned short P[4][16][280];  // per-wave P round-trip buffer

  const int blk  = blockIdx.x;   // 0..2047
  const int h    = blk & 7;
  const int sb   = blk >> 3;     // s*4 + b
  const int s    = sb >> 2;
  const int t0   = sb << 8;
  const int tid  = threadIdx.x;
  const int lane = tid & 63;
  const int wave = tid >> 6;
  const int l15  = lane & 15;
  const int quad = lane >> 4;

  // Hoisted K fragments (B-operand: B[k=d][n=token]); contiguous 16B from global.
  bf16x8 bk[16];
#pragma unroll
  for (int ct = 0; ct < 16; ++ct)
    bk[ct] = *reinterpret_cast<const bf16x8*>(
        QKV + (size_t)(t0 + ct * 16 + l15) * 768 + 256 + h * 32 + quad * 8);

  // Hoisted V fragments (B-operand: B[k=token][n=d]) — per-lane gather, one-time.
  bf16x8 bv[2][8];
#pragma unroll
  for (int dt = 0; dt < 2; ++dt) {
#pragma unroll
    for (int ks = 0; ks < 8; ++ks) {
      bf16x8 v;
#pragma unroll
      for (int j = 0; j < 8; ++j) {
        int tok = ks * 32 + quad * 8 + j;
        v[j] = (short)QKV[(size_t)(t0 + tok) * 768 + 512 + h * 32 + dt * 16 + l15];
      }
      bv[dt][ks] = v;
    }
  }

  for (int qb = 0; qb < 4; ++qb) {
    const int qbase = wave * 64 + qb * 16;

    // Q A-fragment: A[m=l15][k=quad*8+j]; D_head=32 = one MFMA K-step.
    bf16x8 qf = *reinterpret_cast<const bf16x8*>(
        QKV + (size_t)(t0 + qbase + l15) * 768 + h * 32 + quad * 8);

    f32x4 sim[16];
#pragma unroll
    for (int ct = 0; ct < 16; ++ct) {
      f32x4 z = {0.f, 0.f, 0.f, 0.f};
      sim[ct] = __builtin_amdgcn_mfma_f32_16x16x32_bf16(qf, bk[ct], z, 0, 0, 0);
    }

    // scale + mask + softmax (row quad*4+i lives across the quad's 16 lanes)
    float lsum[4];
#pragma unroll
    for (int i = 0; i < 4; ++i) {
      const int qrow = qbase + quad * 4 + i;
      const int* mrow = mask + ((size_t)s * 256 + qrow) * 256 + l15;
      float mx = -3.0e38f;
#pragma unroll
      for (int ct = 0; ct < 16; ++ct) {
        float v = sim[ct][i] * SCALE_F;
        if (mrow[ct * 16] == 0) v = -1.0e10f;
        sim[ct][i] = v;
        mx = fmaxf(mx, v);
      }
#pragma unroll
      for (int off = 1; off < 16; off <<= 1)
        mx = fmaxf(mx, __shfl_xor(mx, off, 64));
      float sum = 0.f;
#pragma unroll
      for (int ct = 0; ct < 16; ++ct) {
        float e = __expf(sim[ct][i] - mx);
        sim[ct][i] = e;
        sum += e;
      }
#pragma unroll
      for (int off = 1; off < 16; off <<= 1)
        sum += __shfl_xor(sum, off, 64);
      lsum[i] = sum;
    }

    // P: C/D layout -> LDS -> A-operand layout (m120-verified round-trip)
#pragma unroll
    for (int i = 0; i < 4; ++i)
#pragma unroll
      for (int ct = 0; ct < 16; ++ct)
        P[wave][quad * 4 + i][ct * 16 + l15] = f2bf(sim[ct][i]);
    __syncthreads();

    f32x4 o0 = {0.f, 0.f, 0.f, 0.f};
    f32x4 o1 = {0.f, 0.f, 0.f, 0.f};
#pragma unroll
    for (int ks = 0; ks < 8; ++ks) {
      bf16x8 pf = *reinterpret_cast<const bf16x8*>(&P[wave][l15][ks * 32 + quad * 8]);
      o0 = __builtin_amdgcn_mfma_f32_16x16x32_bf16(pf, bv[0][ks], o0, 0, 0, 0);
      o1 = __builtin_amdgcn_mfma_f32_16x16x32_bf16(pf, bv[1][ks], o1, 0, 0, 0);
    }

#pragma unroll
    for (int i = 0; i < 4; ++i) {
      float rl = 1.0f / lsum[i];
      int row = t0 + qbase + quad * 4 + i;
      Aout[(size_t)row * 256 + h * 32 + l15]      = f2bf(o0[i] * rl);
      Aout[(size_t)row * 256 + h * 32 + 16 + l15] = f2bf(o1[i] * rl);
    }
    __syncthreads();
  }
}

// ---------------------------------------------------------------------------
extern "C" void kernel_launch(void* const* d_in, const int* in_sizes, int n_in,
                              void* d_out, int out_size, void* d_ws, size_t ws_size,
                              hipStream_t stream) {
  const float* X    = (const float*)d_in[0];  // [65536][256] fp32
  const int*   mask = (const int*)d_in[1];    // [64][256][256] int32
  const float* Wqkv = (const float*)d_in[2];  // [256][768] fp32
  const float* Wout = (const float*)d_in[3];  // [256][256] fp32
  const float* bout = (const float*)d_in[4];  // [256] fp32
  float*       outp = (float*)d_out;          // [65536][256] fp32

  unsigned short* QKV  = (unsigned short*)d_ws;      // 65536*768 bf16 = 100.7MB
  unsigned short* Amid = QKV + (size_t)65536 * 768;  // 65536*256 bf16 = 33.5MB

  dim3 blk(256);
  gemm_kernel<true, false><<<dim3(512, 12), blk, 0, stream>>>(
      (const void*)X, Wqkv, (void*)QKV, nullptr, 65536, 768, 256);
  attn_kernel<<<dim3(2048), blk, 0, stream>>>(QKV, mask, Amid);
  gemm_kernel<false, true><<<dim3(512, 4), blk, 0, stream>>>(
      (const void*)Amid, Wout, (void*)outp, bout, 65536, 256, 256);
}

// Round 5
// 355.309 us; speedup vs baseline: 1.2622x; 1.2622x over previous
//
#include <hip/hip_runtime.h>

typedef __attribute__((ext_vector_type(8))) short bf16x8;
typedef __attribute__((ext_vector_type(4))) float f32x4;

__device__ __forceinline__ unsigned short f2bf(float f) {
  unsigned int u = __builtin_bit_cast(unsigned int, f);
  u += 0x7fffu + ((u >> 16) & 1u);   // round-to-nearest-even
  return (unsigned short)(u >> 16);
}

// ---------------------------------------------------------------------------
// K0: bulk fp32 -> bf16 convert (8 elems/thread)
// ---------------------------------------------------------------------------
__global__ __launch_bounds__(256) void cvt_kernel(const float* __restrict__ X,
                                                  unsigned short* __restrict__ Y) {
  const long long i = ((long long)blockIdx.x * 256 + threadIdx.x) * 8;
  float4 a = *reinterpret_cast<const float4*>(X + i);
  float4 b = *reinterpret_cast<const float4*>(X + i + 4);
  bf16x8 t;
  t[0] = (short)f2bf(a.x); t[1] = (short)f2bf(a.y);
  t[2] = (short)f2bf(a.z); t[3] = (short)f2bf(a.w);
  t[4] = (short)f2bf(b.x); t[5] = (short)f2bf(b.y);
  t[6] = (short)f2bf(b.z); t[7] = (short)f2bf(b.w);
  *reinterpret_cast<bf16x8*>(Y + i) = t;
}

// ---------------------------------------------------------------------------
// K1/K3: GEMM C[M][N] = A[M][K] * B[K][N] (+bias). A bf16, B fp32 (transposed
// + converted in-loop into LDS, exactly round-2's proven staging). fp32 accum.
// Tile 128x128, BK=32, 256 threads; 4 waves as 2x2 of 64x64 per-wave tiles.
// ---------------------------------------------------------------------------
template <bool C_F32>
__global__ __launch_bounds__(256) void gemm_kernel(
    const unsigned short* __restrict__ A,   // [M][K] bf16
    const float* __restrict__ B,            // [K][N] fp32
    void* __restrict__ Cv,
    const float* __restrict__ bias,         // [N] fp32 (C_F32 only)
    int M, int N, int K)
{
  __shared__ __align__(16) unsigned short As[128][40];  // +8 pad
  __shared__ __align__(16) unsigned short Bs[128][40];  // transposed [n][k]

  const int tid  = threadIdx.x;
  const int bm   = blockIdx.x * 128;
  const int bn   = blockIdx.y * 128;
  const int lane = tid & 63;
  const int wave = tid >> 6;
  const int wr   = (wave >> 1) * 64;
  const int wc   = (wave & 1) * 64;
  const int l15  = lane & 15;
  const int quad = lane >> 4;

  f32x4 acc[4][4];
#pragma unroll
  for (int r = 0; r < 4; ++r)
#pragma unroll
    for (int c = 0; c < 4; ++c) {
      f32x4 z = {0.f, 0.f, 0.f, 0.f};
      acc[r][c] = z;
    }

  const int ar   = tid >> 2;        // 0..63  (A stage row)
  const int ac   = (tid & 3) * 8;   // 0/8/16/24
  const int bkr  = tid >> 3;        // 0..31  (B stage k-row)
  const int bn16 = (tid & 7) * 16;  // 0..112

  for (int kk = 0; kk < K; kk += 32) {
    // ---- stage A tile: 128 rows x 32 k (bf16, uint4) ----
    *reinterpret_cast<uint4*>(&As[ar][ac]) =
        *reinterpret_cast<const uint4*>(A + (size_t)(bm + ar) * K + kk + ac);
    *reinterpret_cast<uint4*>(&As[ar + 64][ac]) =
        *reinterpret_cast<const uint4*>(A + (size_t)(bm + ar + 64) * K + kk + ac);
    // ---- stage B tile transposed: Bs[n][k], fp32 -> bf16 (round-2 pattern) ----
    {
      const float* p = B + (size_t)(kk + bkr) * N + bn + bn16;
#pragma unroll
      for (int j = 0; j < 16; j += 4) {
        float4 f = *reinterpret_cast<const float4*>(p + j);
        Bs[bn16 + j + 0][bkr] = f2bf(f.x);
        Bs[bn16 + j + 1][bkr] = f2bf(f.y);
        Bs[bn16 + j + 2][bkr] = f2bf(f.z);
        Bs[bn16 + j + 3][bkr] = f2bf(f.w);
      }
    }
    __syncthreads();

    bf16x8 af[4], bf[4];
#pragma unroll
    for (int i = 0; i < 4; ++i) {
      af[i] = *reinterpret_cast<const bf16x8*>(&As[wr + i * 16 + l15][quad * 8]);
      bf[i] = *reinterpret_cast<const bf16x8*>(&Bs[wc + i * 16 + l15][quad * 8]);
    }
#pragma unroll
    for (int rt = 0; rt < 4; ++rt)
#pragma unroll
      for (int ct = 0; ct < 4; ++ct)
        acc[rt][ct] = __builtin_amdgcn_mfma_f32_16x16x32_bf16(af[rt], bf[ct], acc[rt][ct], 0, 0, 0);
    __syncthreads();
  }

  // epilogue: D[row=quad*4+i][col=l15] per 16x16 tile (round-2 proven)
#pragma unroll
  for (int rt = 0; rt < 4; ++rt)
#pragma unroll
    for (int ct = 0; ct < 4; ++ct)
#pragma unroll
      for (int i = 0; i < 4; ++i) {
        const int row = bm + wr + rt * 16 + quad * 4 + i;
        const int col = bn + wc + ct * 16 + l15;
        const float v = acc[rt][ct][i];
        if constexpr (C_F32) {
          ((float*)Cv)[(size_t)row * N + col] = v + bias[col];
        } else {
          ((unsigned short*)Cv)[(size_t)row * N + col] = f2bf(v);
        }
      }
}

// ---------------------------------------------------------------------------
// K2: masked softmax attention — round-2's kernel with ONE change: K and V
// staged coalesced through LDS (V parks in the P region, consumed into
// registers before P's first use). Mask path, max-subtraction softmax,
// P round-trip and __syncthreads all identical to the proven round-2 code.
// ---------------------------------------------------------------------------
#define SCALE_F 0.17677669529663689f

__global__ __launch_bounds__(256) void attn_kernel(
    const unsigned short* __restrict__ QKV,   // [t][768] bf16: Q|K|V
    const int* __restrict__ mask,             // [64][256][256] int32
    unsigned short* __restrict__ Aout)        // [65536][256] bf16
{
  __shared__ __align__(16) unsigned short Ks[256 * 40];      // K[tok][d], stride 40
  __shared__ __align__(16) unsigned short SH[4 * 16 * 280];  // P per wave (stride 280); V stage at init

  const int blk  = blockIdx.x;   // 0..2047
  const int h    = blk & 7;
  const int sb   = blk >> 3;
  const int s    = sb >> 2;
  const int t0   = sb << 8;
  const int tid  = threadIdx.x;
  const int lane = tid & 63;
  const int wave = tid >> 6;
  const int l15  = lane & 15;
  const int quad = lane >> 4;

  // ---- stage K and V coalesced: thread t = token t, 64B each ----
  {
    const unsigned short* kp = QKV + (size_t)(t0 + tid) * 768 + 256 + h * 32;
    const unsigned short* vp = kp + 256;
    unsigned short* kd = Ks + tid * 40;
    unsigned short* vd = SH + tid * 40;
#pragma unroll
    for (int i = 0; i < 4; ++i) {
      *reinterpret_cast<uint4*>(kd + i * 8) = *reinterpret_cast<const uint4*>(kp + i * 8);
      *reinterpret_cast<uint4*>(vd + i * 8) = *reinterpret_cast<const uint4*>(vp + i * 8);
    }
  }
  __syncthreads();

  // ---- V fragments (B-operand: B[k=tok][n=d]) from staged V ----
  bf16x8 bv[2][8];
#pragma unroll
  for (int dt = 0; dt < 2; ++dt)
#pragma unroll
    for (int ks = 0; ks < 8; ++ks) {
      bf16x8 v;
#pragma unroll
      for (int j = 0; j < 8; ++j)
        v[j] = (short)SH[(ks * 32 + quad * 8 + j) * 40 + dt * 16 + l15];
      bv[dt][ks] = v;
    }
  __syncthreads();   // V stage region now free -> P

  unsigned short* P = SH + wave * (16 * 280);

  for (int qb = 0; qb < 4; ++qb) {
    const int qbase = wave * 64 + qb * 16;

    // Q A-fragment: A[m=l15][k=quad*8+j]
    bf16x8 qf = *reinterpret_cast<const bf16x8*>(
        QKV + (size_t)(t0 + qbase + l15) * 768 + h * 32 + quad * 8);

    f32x4 sim[16];
#pragma unroll
    for (int ct = 0; ct < 16; ++ct) {
      bf16x8 kf = *reinterpret_cast<const bf16x8*>(&Ks[(ct * 16 + l15) * 40 + quad * 8]);
      f32x4 z = {0.f, 0.f, 0.f, 0.f};
      sim[ct] = __builtin_amdgcn_mfma_f32_16x16x32_bf16(qf, kf, z, 0, 0, 0);
    }

    // scale + mask + softmax — identical to round 2
    float lsum[4];
#pragma unroll
    for (int i = 0; i < 4; ++i) {
      const int qrow = qbase + quad * 4 + i;
      const int* mrow = mask + ((size_t)s * 256 + qrow) * 256 + l15;
      float mx = -3.0e38f;
#pragma unroll
      for (int ct = 0; ct < 16; ++ct) {
        float v = sim[ct][i] * SCALE_F;
        if (mrow[ct * 16] == 0) v = -1.0e10f;
        sim[ct][i] = v;
        mx = fmaxf(mx, v);
      }
#pragma unroll
      for (int off = 1; off < 16; off <<= 1)
        mx = fmaxf(mx, __shfl_xor(mx, off, 64));
      float sum = 0.f;
#pragma unroll
      for (int ct = 0; ct < 16; ++ct) {
        float e = __expf(sim[ct][i] - mx);
        sim[ct][i] = e;
        sum += e;
      }
#pragma unroll
      for (int off = 1; off < 16; off <<= 1)
        sum += __shfl_xor(sum, off, 64);
      lsum[i] = sum;
    }

    // P: C/D layout -> LDS -> A-operand layout (round-2 proven round-trip)
#pragma unroll
    for (int i = 0; i < 4; ++i)
#pragma unroll
      for (int ct = 0; ct < 16; ++ct)
        P[(quad * 4 + i) * 280 + ct * 16 + l15] = f2bf(sim[ct][i]);
    __syncthreads();

    f32x4 o0 = {0.f, 0.f, 0.f, 0.f};
    f32x4 o1 = {0.f, 0.f, 0.f, 0.f};
#pragma unroll
    for (int ks = 0; ks < 8; ++ks) {
      bf16x8 pf = *reinterpret_cast<const bf16x8*>(&P[l15 * 280 + ks * 32 + quad * 8]);
      o0 = __builtin_amdgcn_mfma_f32_16x16x32_bf16(pf, bv[0][ks], o0, 0, 0, 0);
      o1 = __builtin_amdgcn_mfma_f32_16x16x32_bf16(pf, bv[1][ks], o1, 0, 0, 0);
    }

#pragma unroll
    for (int i = 0; i < 4; ++i) {
      const float rl = 1.0f / lsum[i];
      const size_t row = (size_t)t0 + qbase + quad * 4 + i;
      Aout[row * 256 + h * 32 + l15]      = f2bf(o0[i] * rl);
      Aout[row * 256 + h * 32 + 16 + l15] = f2bf(o1[i] * rl);
    }
    __syncthreads();
  }
}

// ---------------------------------------------------------------------------
// Workspace: byte-identical span to the PASSING round 2 — exactly 128 MiB.
//   ws[0, 100.66M)        QKV  (live K1 -> attn)
//   ws[100.66M, 134.22M)  Xbf  (live cvt -> K1), then Amid aliases it
// No other buffers anywhere.
// ---------------------------------------------------------------------------
extern "C" void kernel_launch(void* const* d_in, const int* in_sizes, int n_in,
                              void* d_out, int out_size, void* d_ws, size_t ws_size,
                              hipStream_t stream) {
  const float* X    = (const float*)d_in[0];  // [65536][256] fp32
  const int*   mask = (const int*)d_in[1];    // [64][256][256] int32
  const float* Wqkv = (const float*)d_in[2];  // [256][768] fp32
  const float* Wout = (const float*)d_in[3];  // [256][256] fp32
  const float* bout = (const float*)d_in[4];  // [256] fp32
  float*       outp = (float*)d_out;          // [65536][256] fp32

  unsigned short* QKV  = (unsigned short*)d_ws;       // 100.66 MB
  unsigned short* Xbf  = QKV + (size_t)65536 * 768;   // 33.55 MB
  unsigned short* Amid = Xbf;                         // alias: Xbf dead after K1

  dim3 blk(256);
  cvt_kernel<<<dim3(8192), blk, 0, stream>>>(X, Xbf);
  gemm_kernel<false><<<dim3(512, 6), blk, 0, stream>>>(Xbf, Wqkv, (void*)QKV, nullptr, 65536, 768, 256);
  attn_kernel<<<dim3(2048), blk, 0, stream>>>(QKV, mask, Amid);
  gemm_kernel<true><<<dim3(512, 2), blk, 0, stream>>>(Amid, Wout, (void*)outp, bout, 65536, 256, 256);
}

// Round 6
// 321.191 us; speedup vs baseline: 1.3962x; 1.1062x over previous
//
#include <hip/hip_runtime.h>

typedef __attribute__((ext_vector_type(8))) short bf16x8;
typedef __attribute__((ext_vector_type(4))) float f32x4;

__device__ __forceinline__ unsigned short f2bf(float f) {
  unsigned int u = __builtin_bit_cast(unsigned int, f);
  u += 0x7fffu + ((u >> 16) & 1u);   // round-to-nearest-even
  return (unsigned short)(u >> 16);
}

typedef const __attribute__((address_space(1))) unsigned int* as1_u32p;
typedef __attribute__((address_space(3))) unsigned int* as3_u32p;
__device__ __forceinline__ void glds16(const void* g, void* l) {
  __builtin_amdgcn_global_load_lds((as1_u32p)g, (as3_u32p)l, 16, 0, 0);
}

// ---------------------------------------------------------------------------
// K0: bulk fp32 -> bf16 convert (8 elems/thread)
// ---------------------------------------------------------------------------
__global__ __launch_bounds__(256) void cvt_kernel(const float* __restrict__ X,
                                                  unsigned short* __restrict__ Y) {
  const long long i = ((long long)blockIdx.x * 256 + threadIdx.x) * 8;
  float4 a = *reinterpret_cast<const float4*>(X + i);
  float4 b = *reinterpret_cast<const float4*>(X + i + 4);
  bf16x8 t;
  t[0] = (short)f2bf(a.x); t[1] = (short)f2bf(a.y);
  t[2] = (short)f2bf(a.z); t[3] = (short)f2bf(a.w);
  t[4] = (short)f2bf(b.x); t[5] = (short)f2bf(b.y);
  t[6] = (short)f2bf(b.z); t[7] = (short)f2bf(b.w);
  *reinterpret_cast<bf16x8*>(Y + i) = t;
}

// ---------------------------------------------------------------------------
// K0t: fp32 [R][C] -> bf16 [C][R] transpose (32x32 tiles)
// ---------------------------------------------------------------------------
__global__ __launch_bounds__(256) void transpose_bf16_kernel(
    const float* __restrict__ S, unsigned short* __restrict__ D, int R, int C) {
  __shared__ float T[32][33];
  const int bx = blockIdx.x * 32;  // col tile
  const int by = blockIdx.y * 32;  // row tile
  const int tx = threadIdx.x & 31, ty = threadIdx.x >> 5;
#pragma unroll
  for (int k = 0; k < 4; ++k)
    T[ty + 8 * k][tx] = S[(size_t)(by + ty + 8 * k) * C + bx + tx];
  __syncthreads();
#pragma unroll
  for (int k = 0; k < 4; ++k)
    D[(size_t)(bx + ty + 8 * k) * R + by + tx] = f2bf(T[tx][ty + 8 * k]);
}

// ---------------------------------------------------------------------------
// K1/K3: bf16 GEMM  C[M][N] = A[M][K] * Bt[N][K]^T (+bias), fp32 accum.
// m97-style: 128x128 tile, BK=32, global_load_lds width-16 staging into
// UNPADDED contiguous LDS (stride 32 shorts), 16 MFMA/wave/K-step.
// ---------------------------------------------------------------------------
template <bool C_F32>
__global__ __launch_bounds__(256) void gemm_bt(
    const unsigned short* __restrict__ A,   // [M][K] bf16
    const unsigned short* __restrict__ Bt,  // [N][K] bf16
    void* __restrict__ Cv,
    const float* __restrict__ bias,         // [N] fp32 (C_F32 only)
    int M, int N, int K)
{
  __shared__ __align__(16) unsigned short As[128 * 32];  // unpadded (GLDS layout)
  __shared__ __align__(16) unsigned short Bs[128 * 32];

  const int tid  = threadIdx.x;
  const int bm   = blockIdx.x * 128;
  const int bn   = blockIdx.y * 128;
  const int lane = tid & 63;
  const int wave = tid >> 6;
  const int wr   = (wave >> 1) * 64;
  const int wc   = (wave & 1) * 64;
  const int l15  = lane & 15;
  const int quad = lane >> 4;

  f32x4 acc[4][4];
#pragma unroll
  for (int r = 0; r < 4; ++r)
#pragma unroll
    for (int c = 0; c < 4; ++c) {
      f32x4 z = {0.f, 0.f, 0.f, 0.f};
      acc[r][c] = z;
    }

  // per-lane global srcs; wave-uniform LDS dests (dest = base + lane*16B)
  const unsigned short* gA0 = A  + (size_t)(bm + wave * 16 + (lane >> 2)) * K + (lane & 3) * 8;
  const unsigned short* gA1 = gA0 + (size_t)64 * K;
  const unsigned short* gB0 = Bt + (size_t)(bn + wave * 16 + (lane >> 2)) * K + (lane & 3) * 8;
  const unsigned short* gB1 = gB0 + (size_t)64 * K;
  unsigned short* lA0 = As + wave * 512;
  unsigned short* lA1 = As + 2048 + wave * 512;
  unsigned short* lB0 = Bs + wave * 512;
  unsigned short* lB1 = Bs + 2048 + wave * 512;

  for (int kk = 0; kk < K; kk += 32) {
    glds16(gA0 + kk, lA0);
    glds16(gA1 + kk, lA1);
    glds16(gB0 + kk, lB0);
    glds16(gB1 + kk, lB1);
    __syncthreads();   // drains vmcnt before barrier (compiler-enforced)

    bf16x8 af[4], bf[4];
#pragma unroll
    for (int i = 0; i < 4; ++i) {
      af[i] = *reinterpret_cast<const bf16x8*>(&As[(wr + i * 16 + l15) * 32 + quad * 8]);
      bf[i] = *reinterpret_cast<const bf16x8*>(&Bs[(wc + i * 16 + l15) * 32 + quad * 8]);
    }
#pragma unroll
    for (int rt = 0; rt < 4; ++rt)
#pragma unroll
      for (int ct = 0; ct < 4; ++ct)
        acc[rt][ct] = __builtin_amdgcn_mfma_f32_16x16x32_bf16(af[rt], bf[ct], acc[rt][ct], 0, 0, 0);
    __syncthreads();
  }

  // epilogue: D[row=quad*4+i][col=l15] per 16x16 tile (proven layout)
#pragma unroll
  for (int rt = 0; rt < 4; ++rt)
#pragma unroll
    for (int ct = 0; ct < 4; ++ct)
#pragma unroll
      for (int i = 0; i < 4; ++i) {
        const int row = bm + wr + rt * 16 + quad * 4 + i;
        const int col = bn + wc + ct * 16 + l15;
        const float v = acc[rt][ct][i];
        if constexpr (C_F32) {
          ((float*)Cv)[(size_t)row * N + col] = v + bias[col];
        } else {
          ((unsigned short*)Cv)[(size_t)row * N + col] = f2bf(v);
        }
      }
}

// ---------------------------------------------------------------------------
// K2: masked softmax attention — BYTE-IDENTICAL to the passing round-5 kernel.
// ---------------------------------------------------------------------------
#define SCALE_F 0.17677669529663689f

__global__ __launch_bounds__(256) void attn_kernel(
    const unsigned short* __restrict__ QKV,   // [t][768] bf16: Q|K|V
    const int* __restrict__ mask,             // [64][256][256] int32
    unsigned short* __restrict__ Aout)        // [65536][256] bf16
{
  __shared__ __align__(16) unsigned short Ks[256 * 40];      // K[tok][d], stride 40
  __shared__ __align__(16) unsigned short SH[4 * 16 * 280];  // P per wave; V stage at init

  const int blk  = blockIdx.x;   // 0..2047
  const int h    = blk & 7;
  const int sb   = blk >> 3;
  const int s    = sb >> 2;
  const int t0   = sb << 8;
  const int tid  = threadIdx.x;
  const int lane = tid & 63;
  const int wave = tid >> 6;
  const int l15  = lane & 15;
  const int quad = lane >> 4;

  {
    const unsigned short* kp = QKV + (size_t)(t0 + tid) * 768 + 256 + h * 32;
    const unsigned short* vp = kp + 256;
    unsigned short* kd = Ks + tid * 40;
    unsigned short* vd = SH + tid * 40;
#pragma unroll
    for (int i = 0; i < 4; ++i) {
      *reinterpret_cast<uint4*>(kd + i * 8) = *reinterpret_cast<const uint4*>(kp + i * 8);
      *reinterpret_cast<uint4*>(vd + i * 8) = *reinterpret_cast<const uint4*>(vp + i * 8);
    }
  }
  __syncthreads();

  bf16x8 bv[2][8];
#pragma unroll
  for (int dt = 0; dt < 2; ++dt)
#pragma unroll
    for (int ks = 0; ks < 8; ++ks) {
      bf16x8 v;
#pragma unroll
      for (int j = 0; j < 8; ++j)
        v[j] = (short)SH[(ks * 32 + quad * 8 + j) * 40 + dt * 16 + l15];
      bv[dt][ks] = v;
    }
  __syncthreads();   // V stage region now free -> P

  unsigned short* P = SH + wave * (16 * 280);

  for (int qb = 0; qb < 4; ++qb) {
    const int qbase = wave * 64 + qb * 16;

    bf16x8 qf = *reinterpret_cast<const bf16x8*>(
        QKV + (size_t)(t0 + qbase + l15) * 768 + h * 32 + quad * 8);

    f32x4 sim[16];
#pragma unroll
    for (int ct = 0; ct < 16; ++ct) {
      bf16x8 kf = *reinterpret_cast<const bf16x8*>(&Ks[(ct * 16 + l15) * 40 + quad * 8]);
      f32x4 z = {0.f, 0.f, 0.f, 0.f};
      sim[ct] = __builtin_amdgcn_mfma_f32_16x16x32_bf16(qf, kf, z, 0, 0, 0);
    }

    float lsum[4];
#pragma unroll
    for (int i = 0; i < 4; ++i) {
      const int qrow = qbase + quad * 4 + i;
      const int* mrow = mask + ((size_t)s * 256 + qrow) * 256 + l15;
      float mx = -3.0e38f;
#pragma unroll
      for (int ct = 0; ct < 16; ++ct) {
        float v = sim[ct][i] * SCALE_F;
        if (mrow[ct * 16] == 0) v = -1.0e10f;
        sim[ct][i] = v;
        mx = fmaxf(mx, v);
      }
#pragma unroll
      for (int off = 1; off < 16; off <<= 1)
        mx = fmaxf(mx, __shfl_xor(mx, off, 64));
      float sum = 0.f;
#pragma unroll
      for (int ct = 0; ct < 16; ++ct) {
        float e = __expf(sim[ct][i] - mx);
        sim[ct][i] = e;
        sum += e;
      }
#pragma unroll
      for (int off = 1; off < 16; off <<= 1)
        sum += __shfl_xor(sum, off, 64);
      lsum[i] = sum;
    }

#pragma unroll
    for (int i = 0; i < 4; ++i)
#pragma unroll
      for (int ct = 0; ct < 16; ++ct)
        P[(quad * 4 + i) * 280 + ct * 16 + l15] = f2bf(sim[ct][i]);
    __syncthreads();

    f32x4 o0 = {0.f, 0.f, 0.f, 0.f};
    f32x4 o1 = {0.f, 0.f, 0.f, 0.f};
#pragma unroll
    for (int ks = 0; ks < 8; ++ks) {
      bf16x8 pf = *reinterpret_cast<const bf16x8*>(&P[l15 * 280 + ks * 32 + quad * 8]);
      o0 = __builtin_amdgcn_mfma_f32_16x16x32_bf16(pf, bv[0][ks], o0, 0, 0, 0);
      o1 = __builtin_amdgcn_mfma_f32_16x16x32_bf16(pf, bv[1][ks], o1, 0, 0, 0);
    }

#pragma unroll
    for (int i = 0; i < 4; ++i) {
      const float rl = 1.0f / lsum[i];
      const size_t row = (size_t)t0 + qbase + quad * 4 + i;
      Aout[row * 256 + h * 32 + l15]      = f2bf(o0[i] * rl);
      Aout[row * 256 + h * 32 + 16 + l15] = f2bf(o1[i] * rl);
    }
    __syncthreads();
  }
}

// ---------------------------------------------------------------------------
// Memory plan:
//   ws[0, 96MiB)        QKV  (live K1->attn); WoutT transposed into ws[0]
//                             AFTER attn (QKV dead) for K3.
//   ws[96MiB, 128MiB)   Xbf  (live cvt->K1), then Amid aliases it (attn->K3).
//   d_out[0, 384KB)     WqkvT scratch (live ->K1; K1 only READS d_out;
//                             K3 later overwrites all of d_out).
// ---------------------------------------------------------------------------
extern "C" void kernel_launch(void* const* d_in, const int* in_sizes, int n_in,
                              void* d_out, int out_size, void* d_ws, size_t ws_size,
                              hipStream_t stream) {
  const float* X    = (const float*)d_in[0];  // [65536][256] fp32
  const int*   mask = (const int*)d_in[1];    // [64][256][256] int32
  const float* Wqkv = (const float*)d_in[2];  // [256][768] fp32
  const float* Wout = (const float*)d_in[3];  // [256][256] fp32
  const float* bout = (const float*)d_in[4];  // [256] fp32
  float*       outp = (float*)d_out;          // [65536][256] fp32

  unsigned short* QKV   = (unsigned short*)d_ws;       // 96 MiB
  unsigned short* Xbf   = QKV + (size_t)65536 * 768;   // 32 MiB
  unsigned short* Amid  = Xbf;                         // alias: Xbf dead after K1
  unsigned short* WoutT = QKV;                         // alias: QKV dead after attn
  unsigned short* WqkvT = (unsigned short*)d_out;      // d_out scratch, dead before K3

  dim3 blk(256);
  cvt_kernel<<<dim3(8192), blk, 0, stream>>>(X, Xbf);
  transpose_bf16_kernel<<<dim3(24, 8), blk, 0, stream>>>(Wqkv, WqkvT, 256, 768);

  gemm_bt<false><<<dim3(512, 6), blk, 0, stream>>>(Xbf, WqkvT, (void*)QKV, nullptr, 65536, 768, 256);
  attn_kernel<<<dim3(2048), blk, 0, stream>>>(QKV, mask, Amid);

  transpose_bf16_kernel<<<dim3(8, 8), blk, 0, stream>>>(Wout, WoutT, 256, 256);
  gemm_bt<true><<<dim3(512, 2), blk, 0, stream>>>(Amid, WoutT, (void*)outp, bout, 65536, 256, 256);
}